// Round 5
// baseline (334.655 us; speedup 1.0000x reference)
//
#include <hip/hip_runtime.h>
#include <hip/hip_cooperative_groups.h>
#include <math.h>

namespace cg = cooperative_groups;

#define BB 32
#define LL 512
#define HH 768
#define PP 5
#define KK 5
#define CC 4
#define NN (BB*PP)   // 160
#define GRID 256
#define TPB 256

// ws float offsets
#define WS_PNORM 320     // 5 floats   (loss_rows double[160] occupies floats [0,320))
#define WS_SIM   336     // 160
#define WS_CS    512     // 81920
#define WS_MASK  82432   // 81920
#define WS_DENOM 164352  // 160
#define WS_Z     164608  // 122880

__device__ __forceinline__ float wredf(float v) {
  #pragma unroll
  for (int off = 32; off; off >>= 1) v += __shfl_xor(v, off, 64);
  return v;
}
__device__ __forceinline__ double wredd(double v) {
  #pragma unroll
  for (int off = 32; off; off >>= 1) v += __shfl_xor(v, off, 64);
  return v;
}

__global__ __launch_bounds__(TPB, 1) void mega(
    const float* __restrict__ emb, const float* __restrict__ hid,
    const float* __restrict__ proto, const float* __restrict__ W1,
    const float* __restrict__ b1, const float* __restrict__ Wpi,
    const float* __restrict__ bpi, const float* __restrict__ Wmu,
    const float* __restrict__ bmu, const float* __restrict__ Wsig,
    const float* __restrict__ bsig, const float* __restrict__ fcW,
    const float* __restrict__ fcb, float* __restrict__ out,
    float* __restrict__ ws)
{
  cg::grid_group grid = cg::this_grid();
  __shared__ float smem[3584];
  const int tid = threadIdx.x, lane = tid & 63, wid = tid >> 6, bid = blockIdx.x;

  double* loss_rows = (double*)ws;
  float* pnorm_ws = ws + WS_PNORM;
  float* sim_ws   = ws + WS_SIM;
  float* cs_ws    = ws + WS_CS;
  float* mask_ws  = ws + WS_MASK;
  float* denom_ws = ws + WS_DENOM;
  float* Z_ws     = ws + WS_Z;

  // =================== Phase A: cs[b*5+p][l] + pnorm ===================
  {
    float* s_inv = smem + 3520;                       // [5]
    for (int p = wid; p < PP; p += 4) {               // per-block prototype norms
      const float4* pr4 = (const float4*)(proto + p * HH);
      float ss = 0;
      #pragma unroll
      for (int i = 0; i < 3; i++) {
        float4 v = pr4[lane + i * 64];
        ss = fmaf(v.x,v.x,fmaf(v.y,v.y,fmaf(v.z,v.z,fmaf(v.w,v.w,ss))));
      }
      ss = wredf(ss);
      if (lane == 0) {
        float nrm = sqrtf(ss);
        s_inv[p] = 1.0f / fmaxf(nrm, 1e-12f);
        if (bid == 0) pnorm_ws[p] = nrm;
      }
    }
    __syncthreads();
    float invs[PP];
    #pragma unroll
    for (int p = 0; p < PP; p++) invs[p] = s_inv[p];

    const float4* pr4 = (const float4*)proto;
    int tbase = bid * 64 + wid * 16;                  // 16 tokens per wave, 4 groups of 4
    for (int g = 0; g < 4; g++) {
      int t0 = tbase + g * 4;
      float4 x[4][3];
      #pragma unroll
      for (int m = 0; m < 4; m++) {
        const float4* e4 = (const float4*)(emb + (size_t)(t0 + m) * HH);
        #pragma unroll
        for (int i = 0; i < 3; i++) x[m][i] = e4[lane + i * 64];
      }
      float ss[4] = {0,0,0,0};
      float acc[4][PP] = {};
      #pragma unroll
      for (int i = 0; i < 3; i++) {
        float4 w[PP];
        #pragma unroll
        for (int p = 0; p < PP; p++) w[p] = pr4[p * (HH/4) + lane + i * 64];
        #pragma unroll
        for (int m = 0; m < 4; m++) {
          float4 xx = x[m][i];
          ss[m] = fmaf(xx.x,xx.x,fmaf(xx.y,xx.y,fmaf(xx.z,xx.z,fmaf(xx.w,xx.w,ss[m]))));
          #pragma unroll
          for (int p = 0; p < PP; p++) {
            float4 ww = w[p];
            acc[m][p] = fmaf(xx.x,ww.x,fmaf(xx.y,ww.y,fmaf(xx.z,ww.z,fmaf(xx.w,ww.w,acc[m][p]))));
          }
        }
      }
      #pragma unroll
      for (int off = 32; off; off >>= 1) {
        #pragma unroll
        for (int m = 0; m < 4; m++) {
          ss[m] += __shfl_xor(ss[m], off, 64);
          #pragma unroll
          for (int p = 0; p < PP; p++) acc[m][p] += __shfl_xor(acc[m][p], off, 64);
        }
      }
      if (lane == 0) {
        #pragma unroll
        for (int m = 0; m < 4; m++) {
          int tok = t0 + m, b = tok >> 9, l = tok & 511;
          float inv_e = 1.0f / fmaxf(sqrtf(ss[m]), 1e-12f);
          size_t base = ((size_t)b * PP) * LL + l;
          #pragma unroll
          for (int p = 0; p < PP; p++)
            cs_ws[base + (size_t)p * LL] = acc[m][p] * inv_e * invs[p];
        }
      }
    }
  }
  grid.sync();

  // ============ Phase B: h=tanh(cs@W1+b1); MDN; top-5; NLL; mask; denom ============
  if (bid < NN) {
    float* s_cs  = smem;          // 512
    float* s_h   = smem + 512;    // 512
    float* s_out = smem + 1024;   // 15
    float* s_par = smem + 1040;   // 30: logpi[0..4] pi[5..9] mu[10..14] logsig[15..19] invsig[20..24] sig[25..29]
    float* s_dn  = smem + 1072;   // 4
    int n = bid;
    s_cs[tid]       = cs_ws[(size_t)n * LL + tid];
    s_cs[tid + 256] = cs_ws[(size_t)n * LL + tid + 256];
    __syncthreads();
    {
      int j0 = tid * 2;
      const float2* W12 = (const float2*)W1;
      float a0 = 0, a1 = 0;
      #pragma unroll 8
      for (int l = 0; l < LL; l++) {
        float2 w = W12[l * (LL/2) + tid];
        float c = s_cs[l];
        a0 = fmaf(c, w.x, a0); a1 = fmaf(c, w.y, a1);
      }
      s_h[j0]     = tanhf(a0 + b1[j0]);
      s_h[j0 + 1] = tanhf(a1 + b1[j0 + 1]);
    }
    __syncthreads();
    for (int o = wid; o < 15; o += 4) {
      int pj = o / 5, k = o % 5;
      const float* W  = (pj == 0) ? Wpi : ((pj == 1) ? Wmu : Wsig);
      const float* bb = (pj == 0) ? bpi : ((pj == 1) ? bmu : bsig);
      double acc = 0;
      for (int l = lane; l < LL; l += 64) acc += (double)s_h[l] * (double)W[l * KK + k];
      acc = wredd(acc);
      if (lane == 0) s_out[o] = (float)(acc + (double)bb[k]);
    }
    __syncthreads();
    if (tid == 0) {
      float x[KK], sh[KK], mx = -INFINITY;
      #pragma unroll
      for (int k = 0; k < KK; k++) { x[k] = s_out[k]; mx = fmaxf(mx, x[k]); }
      float se = 0;
      #pragma unroll
      for (int k = 0; k < KK; k++) { sh[k] = x[k] - mx; se += expf(sh[k]); }
      float lse = logf(se);
      #pragma unroll
      for (int k = 0; k < KK; k++) {
        float lp = sh[k] - lse;
        s_par[k]      = lp;            // logpi
        s_par[5 + k]  = expf(lp);      // pi
        s_par[10 + k] = s_out[5 + k];  // mu
        float ls = s_out[10 + k];
        s_par[15 + k] = ls;            // logsig
        float sg = expf(ls);
        s_par[25 + k] = sg;            // sig
        s_par[20 + k] = 1.0f / sg;     // invsig
      }
    }
    __syncthreads();
    if (wid == 0) {                    // top-5 + NLL (double)
      float v[8];
      #pragma unroll
      for (int i = 0; i < 8; i++) v[i] = s_cs[lane + i * 64];
      float ys[KK];
      for (int it = 0; it < KK; ++it) {
        float bv = v[0]; int bi = lane;
        #pragma unroll
        for (int i = 1; i < 8; i++) { if (v[i] > bv) { bv = v[i]; bi = lane + i * 64; } }
        #pragma unroll
        for (int off = 32; off; off >>= 1) {
          float ov = __shfl_xor(bv, off, 64);
          int   oi = __shfl_xor(bi, off, 64);
          if (ov > bv || (ov == bv && oi < bi)) { bv = ov; bi = oi; }
        }
        ys[it] = (float)bi;
        if ((bi & 63) == lane) v[bi >> 6] = -INFINITY;
      }
      double ll = 0;
      if (lane < KK) {
        double y = (double)ys[lane];
        double a[KK], m = -1e300;
        #pragma unroll
        for (int j = 0; j < KK; j++) {
          double z = (y - (double)s_par[10 + j]) / (double)s_par[25 + j];
          a[j] = (double)s_par[j] - 0.5 * z * z - (double)s_par[15 + j]
                 - 0.91893853320467274178;
          if (a[j] > m) m = a[j];
        }
        double se = 0;
        #pragma unroll
        for (int j = 0; j < KK; j++) se += exp(a[j] - m);
        ll = m + log(se);
      }
      ll = wredd(ll);
      if (lane == 0) loss_rows[n] = ll;
    }
    float p_local = 0;
    #pragma unroll
    for (int rr = 0; rr < 2; rr++) {
      int l = tid + rr * 256;
      float t = (float)l, d = 0;
      #pragma unroll
      for (int k = 0; k < KK; k++) {
        float zt = (t - s_par[10 + k]) * s_par[20 + k];
        d += s_par[5 + k] * expf(-0.5f * zt * zt) * s_par[20 + k];
      }
      d *= 0.39894228040143268f;
      mask_ws[(size_t)n * LL + l] = d;
      p_local += d;
    }
    p_local = wredf(p_local);
    if (lane == 0) s_dn[wid] = p_local;
    __syncthreads();
    if (tid == 0)
      denom_ws[n] = fmaxf(s_dn[0] + s_dn[1] + s_dn[2] + s_dn[3], 1e-9f);
  }
  grid.sync();

  // =================== Phase C: Z[b,p,h] pooling (exact 256 items) ===================
  {
    int b = bid & 31, hc = bid >> 5;                  // hc in [0,8): 96-h chunks
    float* s_m   = smem;                              // [5][512]
    float* s_acc = smem + 2560;                       // [2][5][96]
    #pragma unroll
    for (int i = 0; i < 10; i++)
      s_m[tid + i * 256] = mask_ws[(size_t)b * (PP*LL) + tid + i * 256];
    __syncthreads();
    if (tid < 192) {
      int lgrp = tid / 96, hh = tid % 96;
      int h = hc * 96 + hh;
      const float* hb = hid + ((size_t)b * LL + lgrp * 256) * HH + h;
      float acc[PP] = {0,0,0,0,0};
      for (int i0 = 0; i0 < 256; i0 += 16) {
        #pragma unroll
        for (int ii = 0; ii < 16; ii++) {
          int l = lgrp * 256 + i0 + ii;
          float hv = hb[(size_t)(i0 + ii) * HH];
          #pragma unroll
          for (int p = 0; p < PP; p++)
            acc[p] = fmaf(hv, s_m[p * LL + l], acc[p]);
        }
      }
      #pragma unroll
      for (int p = 0; p < PP; p++) s_acc[(lgrp * PP + p) * 96 + hh] = acc[p];
    }
    __syncthreads();
    for (int o = tid; o < PP * 96; o += 256) {
      int p = o / 96, hh = o % 96;
      float s = s_acc[p * 96 + hh] + s_acc[(PP + p) * 96 + hh];
      Z_ws[((size_t)(b * PP + p)) * HH + hc * 96 + hh] =
          s * (1.0f / 512.0f) / denom_ws[b * PP + p];
    }
  }
  grid.sync();

  // =================== Phase D: cosine(Z[g], proto[g%5]) ===================
  if (bid < NN) {
    int g = bid, p = g % PP;
    const float* z  = Z_ws + (size_t)g * HH;
    const float* pr = proto + p * HH;
    float num = 0, zz = 0;
    #pragma unroll
    for (int i = 0; i < 3; i++) {
      int off = wid * 192 + i * 64 + lane;
      float zv = z[off];
      num = fmaf(zv, pr[off], num); zz = fmaf(zv, zv, zz);
    }
    num = wredf(num); zz = wredf(zz);
    if (lane == 0) { smem[wid] = num; smem[8 + wid] = zz; }
    __syncthreads();
    if (tid == 0) {
      float n4 = smem[0] + smem[1] + smem[2] + smem[3];
      float z4 = smem[8] + smem[9] + smem[10] + smem[11];
      sim_ws[g] = n4 / fmaxf(sqrtf(z4) * pnorm_ws[p], 1e-6f);
    }
  }
  grid.sync();

  // =================== Phase E: logits + losses (block 0) ===================
  if (bid == 0) {
    if (tid < BB * CC) {
      int b = tid >> 2, c = tid & 3;
      float s = fcb[c];
      #pragma unroll
      for (int p = 0; p < PP; p++) s = fmaf(sim_ws[b * PP + p], fcW[p * CC + c], s);
      out[tid] = s;
    }
    if (wid == 2) {
      double s = 0;
      for (int i = lane; i < NN; i += 64) s += loss_rows[i];
      s = wredd(s);
      if (lane == 0) out[128] = (float)(-s / 800.0);
    }
    if (wid == 3) {
      const int pi_[10] = {0,0,0,0,1,1,1,2,2,3};
      const int pj_[10] = {1,2,3,4,2,3,4,3,4,4};
      float total = 0;
      #pragma unroll
      for (int q = 0; q < 10; q++) {
        const float* a = proto + pi_[q] * HH;
        const float* c = proto + pj_[q] * HH;
        float ss = 0;
        #pragma unroll
        for (int i = 0; i < 12; i++) {
          float d = a[lane + i * 64] - c[lane + i * 64];
          ss = fmaf(d, d, ss);
        }
        ss = wredf(ss);
        float D = sqrtf(fmaxf(ss, 1e-12f));
        total += fmaxf(0.5f - D, 0.0f);
      }
      if (lane == 0) out[129] = total;
    }
  }
}

extern "C" void kernel_launch(void* const* d_in, const int* in_sizes, int n_in,
                              void* d_out, int out_size, void* d_ws, size_t ws_size,
                              hipStream_t stream)
{
  const float* emb   = (const float*)d_in[0];
  const float* hid   = (const float*)d_in[1];
  const float* proto = (const float*)d_in[2];
  const float* W1    = (const float*)d_in[3];
  const float* b1    = (const float*)d_in[4];
  const float* Wpi   = (const float*)d_in[5];
  const float* bpi   = (const float*)d_in[6];
  const float* Wmu   = (const float*)d_in[7];
  const float* bmu   = (const float*)d_in[8];
  const float* Wsig  = (const float*)d_in[9];
  const float* bsig  = (const float*)d_in[10];
  const float* fcW   = (const float*)d_in[11];
  const float* fcb   = (const float*)d_in[12];
  float* out = (float*)d_out;
  float* wsf = (float*)d_ws;

  void* args[] = {
    (void*)&emb, (void*)&hid, (void*)&proto, (void*)&W1, (void*)&b1,
    (void*)&Wpi, (void*)&bpi, (void*)&Wmu, (void*)&bmu, (void*)&Wsig,
    (void*)&bsig, (void*)&fcW, (void*)&fcb, (void*)&out, (void*)&wsf
  };
  hipLaunchCooperativeKernel((void*)mega, dim3(GRID), dim3(TPB), args, 0, stream);
}

// Round 7
// 183.307 us; speedup vs baseline: 1.8257x; 1.8257x over previous
//
#include <hip/hip_runtime.h>
#include <math.h>

#define BB 32
#define LL 512
#define HH 768
#define PP 5
#define KK 5
#define CC 4
#define NN (BB*PP)   // 160

__device__ __forceinline__ float wredf(float v) {
  #pragma unroll
  for (int off = 32; off; off >>= 1) v += __shfl_xor(v, off, 64);
  return v;
}
__device__ __forceinline__ double wredd(double v) {
  #pragma unroll
  for (int off = 32; off; off >>= 1) v += __shfl_xor(v, off, 64);
  return v;
}

// ==== node 1: cs_raw (4096 blocks) + pnorm (5) + diversity (10) + counter zero (1)
__global__ __launch_bounds__(256) void k1f(const float* __restrict__ emb,
    const float* __restrict__ proto, float* __restrict__ cs,
    float* __restrict__ pnorm, float* __restrict__ divp, int* __restrict__ counter)
{
  __shared__ float s_red[4];
  int tid = threadIdx.x, lane = tid & 63, wid = tid >> 6, bid = blockIdx.x;
  if (bid < 4096) {
    // wave per token: cs_raw[b*5+p][l] = dot(emb[b,l], proto[p]) / |emb[b,l]|
    int gw = bid * 4 + wid, b = gw >> 9, l = gw & 511;
    const float4* e4  = (const float4*)(emb + ((size_t)b * LL + l) * HH);
    const float4* pr4 = (const float4*)proto;
    float ss = 0, acc[PP] = {0, 0, 0, 0, 0};
    #pragma unroll
    for (int i = 0; i < 3; i++) {
      int idx = lane + i * 64;
      float4 x = e4[idx];
      ss = fmaf(x.x, x.x, fmaf(x.y, x.y, fmaf(x.z, x.z, fmaf(x.w, x.w, ss))));
      #pragma unroll
      for (int p = 0; p < PP; p++) {
        float4 w = pr4[p * (HH/4) + idx];
        acc[p] = fmaf(x.x, w.x, fmaf(x.y, w.y, fmaf(x.z, w.z, fmaf(x.w, w.w, acc[p]))));
      }
    }
    #pragma unroll
    for (int off = 32; off; off >>= 1) {
      ss += __shfl_xor(ss, off, 64);
      #pragma unroll
      for (int p = 0; p < PP; p++) acc[p] += __shfl_xor(acc[p], off, 64);
    }
    if (lane == 0) {
      float inv = 1.0f / fmaxf(sqrtf(ss), 1e-12f);
      size_t base = ((size_t)b * PP) * LL + l;
      #pragma unroll
      for (int p = 0; p < PP; p++) cs[base + (size_t)p * LL] = acc[p] * inv;
    }
  } else {
    int aux = bid - 4096;
    if (aux == 15) { if (tid == 0) counter[0] = 0; return; }
    if (aux < PP) {                       // pnorm[aux]
      float ss = 0;
      for (int i = tid; i < HH; i += 256) { float v = proto[aux*HH + i]; ss = fmaf(v, v, ss); }
      ss = wredf(ss);
      if (lane == 0) s_red[wid] = ss;
      __syncthreads();
      if (tid == 0) pnorm[aux] = sqrtf(s_red[0] + s_red[1] + s_red[2] + s_red[3]);
    } else {                              // diversity pair
      const int pi_[10] = {0,0,0,0,1,1,1,2,2,3};
      const int pj_[10] = {1,2,3,4,2,3,4,3,4,4};
      int q = aux - PP, i = pi_[q], j = pj_[q];
      float ss = 0;
      for (int t = tid; t < HH; t += 256) {
        float d = proto[i*HH + t] - proto[j*HH + t];
        ss = fmaf(d, d, ss);
      }
      ss = wredf(ss);
      if (lane == 0) s_red[wid] = ss;
      __syncthreads();
      if (tid == 0) {
        float D = sqrtf(fmaxf(s_red[0] + s_red[1] + s_red[2] + s_red[3], 1e-12f));
        divp[q] = fmaxf(0.5f - D, 0.0f);
      }
    }
  }
}

// ==== node 2: per-row fused GEMV + MDN (160 blocks x 512 threads)
__global__ __launch_bounds__(512) void k2f(
    const float* __restrict__ cs_g, const float* __restrict__ pnorm,
    const float* __restrict__ W1, const float* __restrict__ b1,
    const float* __restrict__ Wpi, const float* __restrict__ bpi,
    const float* __restrict__ Wmu, const float* __restrict__ bmu,
    const float* __restrict__ Wsig, const float* __restrict__ bsig,
    float* __restrict__ mask_g, float* __restrict__ denom_g, double* __restrict__ loss_rows)
{
  __shared__ float s_cs[LL], s_h[LL];
  __shared__ float s_out[16];
  __shared__ float s_par[32]; // logpi[0..4] pi[5..9] mu[10..14] logsig[15..19] invsig[20..24] sig[25..29]
  __shared__ float s_dn[8];
  int tid = threadIdx.x, lane = tid & 63, wid = tid >> 6, n = blockIdx.x;
  float invp = 1.0f / fmaxf(pnorm[n % PP], 1e-12f);
  s_cs[tid] = cs_g[(size_t)n * LL + tid] * invp;   // finish cosine: apply 1/|proto|
  __syncthreads();
  // GEMV: thread = column
  {
    float a0 = 0, a1 = 0, a2 = 0, a3 = 0;
    #pragma unroll 4
    for (int l = 0; l < LL; l += 4) {
      a0 = fmaf(s_cs[l+0], W1[(size_t)(l+0) * LL + tid], a0);
      a1 = fmaf(s_cs[l+1], W1[(size_t)(l+1) * LL + tid], a1);
      a2 = fmaf(s_cs[l+2], W1[(size_t)(l+2) * LL + tid], a2);
      a3 = fmaf(s_cs[l+3], W1[(size_t)(l+3) * LL + tid], a3);
    }
    s_h[tid] = tanhf((a0 + a1) + (a2 + a3) + b1[tid]);
  }
  __syncthreads();
  // 15 projection dots (8 waves, 2 rounds), double accumulation
  for (int o = wid; o < 15; o += 8) {
    int pj = o / 5, k = o % 5;
    const float* W  = (pj == 0) ? Wpi : ((pj == 1) ? Wmu : Wsig);
    const float* bb = (pj == 0) ? bpi : ((pj == 1) ? bmu : bsig);
    double acc = 0;
    for (int l = lane; l < LL; l += 64) acc += (double)s_h[l] * (double)W[l * KK + k];
    acc = wredd(acc);
    if (lane == 0) s_out[o] = (float)(acc + (double)bb[k]);
  }
  __syncthreads();
  if (tid == 0) {
    float x[KK], sh[KK], mx = -INFINITY;
    #pragma unroll
    for (int k = 0; k < KK; k++) { x[k] = s_out[k]; mx = fmaxf(mx, x[k]); }
    float se = 0;
    #pragma unroll
    for (int k = 0; k < KK; k++) { sh[k] = x[k] - mx; se += expf(sh[k]); }
    float lse = logf(se);
    #pragma unroll
    for (int k = 0; k < KK; k++) {
      float lp = sh[k] - lse;
      s_par[k]      = lp;
      s_par[5 + k]  = expf(lp);
      s_par[10 + k] = s_out[5 + k];
      float ls = s_out[10 + k];
      s_par[15 + k] = ls;
      float sg = expf(ls);
      s_par[25 + k] = sg;
      s_par[20 + k] = 1.0f / sg;
    }
  }
  __syncthreads();
  // wave 0: top-5 (JAX tie-break) + NLL in double
  if (wid == 0) {
    float v[8];
    #pragma unroll
    for (int i = 0; i < 8; i++) v[i] = s_cs[lane + i * 64];
    float ys[KK];
    for (int it = 0; it < KK; ++it) {
      float bv = v[0]; int bi = lane;
      #pragma unroll
      for (int i = 1; i < 8; i++) { if (v[i] > bv) { bv = v[i]; bi = lane + i * 64; } }
      #pragma unroll
      for (int off = 32; off; off >>= 1) {
        float ov = __shfl_xor(bv, off, 64);
        int   oi = __shfl_xor(bi, off, 64);
        if (ov > bv || (ov == bv && oi < bi)) { bv = ov; bi = oi; }
      }
      ys[it] = (float)bi;
      if ((bi & 63) == lane) v[bi >> 6] = -INFINITY;
    }
    double ll = 0;
    if (lane < KK) {
      double y = (double)ys[lane];
      double a[KK], m = -1e300;
      #pragma unroll
      for (int j = 0; j < KK; j++) {
        double z = (y - (double)s_par[10 + j]) / (double)s_par[25 + j];
        a[j] = (double)s_par[j] - 0.5 * z * z - (double)s_par[15 + j]
               - 0.91893853320467274178;  // 0.5*log(2*pi)
        if (a[j] > m) m = a[j];
      }
      double se = 0;
      #pragma unroll
      for (int j = 0; j < KK; j++) se += exp(a[j] - m);
      ll = m + log(se);
    }
    ll = wredd(ll);
    if (lane == 0) loss_rows[n] = ll;
  }
  // mask: one token position per thread
  {
    float t = (float)tid, d = 0;
    #pragma unroll
    for (int k = 0; k < KK; k++) {
      float zt = (t - s_par[10 + k]) * s_par[20 + k];
      d += s_par[5 + k] * expf(-0.5f * zt * zt) * s_par[20 + k];
    }
    d *= 0.39894228040143268f;   // 1/sqrt(2*pi)
    mask_g[(size_t)n * LL + tid] = d;
    float r = wredf(d);
    if (lane == 0) s_dn[wid] = r;
  }
  __syncthreads();
  if (tid == 0)
    denom_g[n] = fmaxf(s_dn[0]+s_dn[1]+s_dn[2]+s_dn[3]+s_dn[4]+s_dn[5]+s_dn[6]+s_dn[7], 1e-9f);
}

// ==== node 3: Z[b,p,h] = sum_l hidden[b,l,h]*mask[b,p,l] /L /denom (R3-verified)
__global__ __launch_bounds__(512) void k3_pool(const float* __restrict__ hidden,
    const float* __restrict__ mask_g, const float* __restrict__ denom_g, float* __restrict__ Z)
{
  __shared__ float s_m[PP][LL];        // 10 KB
  __shared__ float s_acc[8][PP][128];  // 20 KB
  int b = blockIdx.x, hc = blockIdx.y;
  int tid = threadIdx.x, wid = tid >> 6, lane = tid & 63;
  for (int i = tid; i < PP * LL; i += 512) s_m[i >> 9][i & (LL - 1)] = mask_g[(size_t)b * PP * LL + i];
  __syncthreads();
  int h0 = hc * 128 + lane * 2;
  const float* hp = hidden + (size_t)b * LL * HH + h0;
  float a0[PP] = {0,0,0,0,0}, a1[PP] = {0,0,0,0,0};
  int lbase = wid * 64;
  #pragma unroll 8
  for (int i = 0; i < 64; i++) {
    int l = lbase + i;
    float2 hv = *(const float2*)(hp + (size_t)l * HH);
    #pragma unroll
    for (int p = 0; p < PP; p++) {
      float m = s_m[p][l];
      a0[p] = fmaf(hv.x, m, a0[p]); a1[p] = fmaf(hv.y, m, a1[p]);
    }
  }
  #pragma unroll
  for (int p = 0; p < PP; p++) { s_acc[wid][p][lane*2] = a0[p]; s_acc[wid][p][lane*2+1] = a1[p]; }
  __syncthreads();
  for (int o = tid; o < PP * 128; o += 512) {
    int p = o >> 7, hl = o & 127;
    float s = 0;
    #pragma unroll
    for (int w = 0; w < 8; w++) s += s_acc[w][p][hl];
    Z[((size_t)b * PP + p) * HH + hc * 128 + hl] = s * (1.0f / 512.0f) / denom_g[b * PP + p];
  }
}

// ==== node 4: cosine sim (40 blocks, wave/row) + last-block head
__global__ __launch_bounds__(256) void k45(const float* __restrict__ Zg,
    const float* __restrict__ proto, const float* __restrict__ pnorm,
    const float* __restrict__ fcW, const float* __restrict__ fcb,
    const double* __restrict__ loss_rows, const float* __restrict__ divp,
    float* __restrict__ sim, int* __restrict__ counter, float* __restrict__ out)
{
  __shared__ int s_last;
  int tid = threadIdx.x, lane = tid & 63, wid = tid >> 6;
  int g = blockIdx.x * 4 + wid, p = g % PP;
  const float* z  = Zg + (size_t)g * HH;
  const float* pr = proto + p * HH;
  float num = 0, zz = 0;
  #pragma unroll
  for (int i = 0; i < 12; i++) {
    int o = lane + i * 64;
    float zv = z[o];
    num = fmaf(zv, pr[o], num); zz = fmaf(zv, zv, zz);
  }
  num = wredf(num); zz = wredf(zz);
  if (lane == 0) sim[g] = num / fmaxf(sqrtf(zz) * pnorm[p], 1e-6f);
  __syncthreads();
  if (tid == 0) { __threadfence(); s_last = (atomicAdd(counter, 1) == (NN/4 - 1)); }
  __syncthreads();
  if (s_last) {
    __threadfence();   // acquire: other blocks' sim/loss writes
    if (tid < BB * CC) {
      int b = tid >> 2, c = tid & 3;
      float s = fcb[c];
      #pragma unroll
      for (int q = 0; q < PP; q++) s = fmaf(sim[b * PP + q], fcW[q * CC + c], s);
      out[tid] = s;
    }
    if (wid == 2) {
      double s = 0;
      for (int i = lane; i < NN; i += 64) s += loss_rows[i];
      s = wredd(s);
      if (lane == 0) out[128] = (float)(-s / 800.0);
    }
    if (wid == 3) {
      float s = (lane < 10) ? divp[lane] : 0.0f;
      s = wredf(s);
      if (lane == 0) out[129] = s;
    }
  }
}

extern "C" void kernel_launch(void* const* d_in, const int* in_sizes, int n_in,
                              void* d_out, int out_size, void* d_ws, size_t ws_size,
                              hipStream_t stream)
{
  const float* emb   = (const float*)d_in[0];
  const float* hid   = (const float*)d_in[1];
  const float* proto = (const float*)d_in[2];
  const float* W1    = (const float*)d_in[3];
  const float* b1    = (const float*)d_in[4];
  const float* Wpi   = (const float*)d_in[5];
  const float* bpi   = (const float*)d_in[6];
  const float* Wmu   = (const float*)d_in[7];
  const float* bmu   = (const float*)d_in[8];
  const float* Wsig  = (const float*)d_in[9];
  const float* bsig  = (const float*)d_in[10];
  const float* fcW   = (const float*)d_in[11];
  const float* fcb   = (const float*)d_in[12];
  float* out = (float*)d_out;

  // ws layout (float offsets)
  double* loss_rows = (double*)d_ws;        // floats [0,320)
  float* wsf    = (float*)d_ws;
  float* divp   = wsf + 320;                // 10
  float* pnorm  = wsf + 330;                // 5
  int*   counter= (int*)(wsf + 336);        // 1
  float* cs     = wsf + 512;                // 81920
  float* maskb  = cs + (size_t)NN * LL;     // 81920
  float* denom  = maskb + (size_t)NN * LL;  // 160
  float* simb   = denom + NN;               // 160
  float* Zb     = simb + NN;                // 122880

  k1f<<<4112, 256, 0, stream>>>(emb, proto, cs, pnorm, divp, counter);
  k2f<<<NN, 512, 0, stream>>>(cs, pnorm, W1, b1, Wpi, bpi, Wmu, bmu, Wsig, bsig,
                              maskb, denom, loss_rows);
  k3_pool<<<dim3(BB, 6), 512, 0, stream>>>(hid, maskb, denom, Zb);
  k45<<<NN / 4, 256, 0, stream>>>(Zb, proto, pnorm, fcW, fcb, loss_rows, divp,
                                  simb, counter, out);
}

// Round 10
// 182.362 us; speedup vs baseline: 1.8351x; 1.0052x over previous
//
#include <hip/hip_runtime.h>
#include <math.h>

#define BB 32
#define LL 512
#define HH 768
#define PP 5
#define KK 5
#define CC 4
#define NN (BB*PP)   // 160

__device__ __forceinline__ float wredf(float v) {
  #pragma unroll
  for (int off = 32; off; off >>= 1) v += __shfl_xor(v, off, 64);
  return v;
}
__device__ __forceinline__ double wredd(double v) {
  #pragma unroll
  for (int off = 32; off; off >>= 1) v += __shfl_xor(v, off, 64);
  return v;
}

// ==== node 1: cs_raw (4096 blocks) + pnorm (5) + diversity (10) + zero counter/numzz
__global__ __launch_bounds__(256) void k1f(const float* __restrict__ emb,
    const float* __restrict__ proto, float* __restrict__ cs,
    float* __restrict__ pnorm, float* __restrict__ divp,
    int* __restrict__ counter, float* __restrict__ numzz)
{
  __shared__ float s_red[4];
  int tid = threadIdx.x, lane = tid & 63, wid = tid >> 6, bid = blockIdx.x;
  if (bid < 4096) {
    // wave per token: cs_raw[b*5+p][l] = dot(emb[b,l], proto[p]) / |emb[b,l]|
    int gw = bid * 4 + wid, b = gw >> 9, l = gw & 511;
    const float4* e4  = (const float4*)(emb + ((size_t)b * LL + l) * HH);
    const float4* pr4 = (const float4*)proto;
    float ss = 0, acc[PP] = {0, 0, 0, 0, 0};
    #pragma unroll
    for (int i = 0; i < 3; i++) {
      int idx = lane + i * 64;
      float4 x = e4[idx];
      ss = fmaf(x.x, x.x, fmaf(x.y, x.y, fmaf(x.z, x.z, fmaf(x.w, x.w, ss))));
      #pragma unroll
      for (int p = 0; p < PP; p++) {
        float4 w = pr4[p * (HH/4) + idx];
        acc[p] = fmaf(x.x, w.x, fmaf(x.y, w.y, fmaf(x.z, w.z, fmaf(x.w, w.w, acc[p]))));
      }
    }
    #pragma unroll
    for (int off = 32; off; off >>= 1) {
      ss += __shfl_xor(ss, off, 64);
      #pragma unroll
      for (int p = 0; p < PP; p++) acc[p] += __shfl_xor(acc[p], off, 64);
    }
    if (lane == 0) {
      float inv = 1.0f / fmaxf(sqrtf(ss), 1e-12f);
      size_t base = ((size_t)b * PP) * LL + l;
      #pragma unroll
      for (int p = 0; p < PP; p++) cs[base + (size_t)p * LL] = acc[p] * inv;
    }
  } else {
    int aux = bid - 4096;
    if (aux == 15) {       // zero the k3 accumulators
      if (tid == 0) counter[0] = 0;
      if (tid < 2 * NN) numzz[tid] = 0.0f;
      return;
    }
    if (aux < PP) {                       // pnorm[aux]
      float ss = 0;
      for (int i = tid; i < HH; i += 256) { float v = proto[aux*HH + i]; ss = fmaf(v, v, ss); }
      ss = wredf(ss);
      if (lane == 0) s_red[wid] = ss;
      __syncthreads();
      if (tid == 0) pnorm[aux] = sqrtf(s_red[0] + s_red[1] + s_red[2] + s_red[3]);
    } else {                              // diversity pair
      const int pi_[10] = {0,0,0,0,1,1,1,2,2,3};
      const int pj_[10] = {1,2,3,4,2,3,4,3,4,4};
      int q = aux - PP, i = pi_[q], j = pj_[q];
      float ss = 0;
      for (int t = tid; t < HH; t += 256) {
        float d = proto[i*HH + t] - proto[j*HH + t];
        ss = fmaf(d, d, ss);
      }
      ss = wredf(ss);
      if (lane == 0) s_red[wid] = ss;
      __syncthreads();
      if (tid == 0) {
        float D = sqrtf(fmaxf(s_red[0] + s_red[1] + s_red[2] + s_red[3], 1e-12f));
        divp[q] = fmaxf(0.5f - D, 0.0f);
      }
    }
  }
}

// ==== node 2: per-row fused GEMV + MDN (160 blocks x 512 threads) — unchanged (R7-verified)
__global__ __launch_bounds__(512) void k2f(
    const float* __restrict__ cs_g, const float* __restrict__ pnorm,
    const float* __restrict__ W1, const float* __restrict__ b1,
    const float* __restrict__ Wpi, const float* __restrict__ bpi,
    const float* __restrict__ Wmu, const float* __restrict__ bmu,
    const float* __restrict__ Wsig, const float* __restrict__ bsig,
    float* __restrict__ mask_g, float* __restrict__ denom_g, double* __restrict__ loss_rows)
{
  __shared__ float s_cs[LL], s_h[LL];
  __shared__ float s_out[16];
  __shared__ float s_par[32]; // logpi[0..4] pi[5..9] mu[10..14] logsig[15..19] invsig[20..24] sig[25..29]
  __shared__ float s_dn[8];
  int tid = threadIdx.x, lane = tid & 63, wid = tid >> 6, n = blockIdx.x;
  float invp = 1.0f / fmaxf(pnorm[n % PP], 1e-12f);
  s_cs[tid] = cs_g[(size_t)n * LL + tid] * invp;   // finish cosine: apply 1/|proto|
  __syncthreads();
  // GEMV: thread = column
  {
    float a0 = 0, a1 = 0, a2 = 0, a3 = 0;
    #pragma unroll 4
    for (int l = 0; l < LL; l += 4) {
      a0 = fmaf(s_cs[l+0], W1[(size_t)(l+0) * LL + tid], a0);
      a1 = fmaf(s_cs[l+1], W1[(size_t)(l+1) * LL + tid], a1);
      a2 = fmaf(s_cs[l+2], W1[(size_t)(l+2) * LL + tid], a2);
      a3 = fmaf(s_cs[l+3], W1[(size_t)(l+3) * LL + tid], a3);
    }
    s_h[tid] = tanhf((a0 + a1) + (a2 + a3) + b1[tid]);
  }
  __syncthreads();
  // 15 projection dots (8 waves, 2 rounds), double accumulation
  for (int o = wid; o < 15; o += 8) {
    int pj = o / 5, k = o % 5;
    const float* W  = (pj == 0) ? Wpi : ((pj == 1) ? Wmu : Wsig);
    const float* bb = (pj == 0) ? bpi : ((pj == 1) ? bmu : bsig);
    double acc = 0;
    for (int l = lane; l < LL; l += 64) acc += (double)s_h[l] * (double)W[l * KK + k];
    acc = wredd(acc);
    if (lane == 0) s_out[o] = (float)(acc + (double)bb[k]);
  }
  __syncthreads();
  if (tid == 0) {
    float x[KK], sh[KK], mx = -INFINITY;
    #pragma unroll
    for (int k = 0; k < KK; k++) { x[k] = s_out[k]; mx = fmaxf(mx, x[k]); }
    float se = 0;
    #pragma unroll
    for (int k = 0; k < KK; k++) { sh[k] = x[k] - mx; se += expf(sh[k]); }
    float lse = logf(se);
    #pragma unroll
    for (int k = 0; k < KK; k++) {
      float lp = sh[k] - lse;
      s_par[k]      = lp;
      s_par[5 + k]  = expf(lp);
      s_par[10 + k] = s_out[5 + k];
      float ls = s_out[10 + k];
      s_par[15 + k] = ls;
      float sg = expf(ls);
      s_par[25 + k] = sg;
      s_par[20 + k] = 1.0f / sg;
    }
  }
  __syncthreads();
  // wave 0: top-5 (JAX tie-break) + NLL in double
  if (wid == 0) {
    float v[8];
    #pragma unroll
    for (int i = 0; i < 8; i++) v[i] = s_cs[lane + i * 64];
    float ys[KK];
    for (int it = 0; it < KK; ++it) {
      float bv = v[0]; int bi = lane;
      #pragma unroll
      for (int i = 1; i < 8; i++) { if (v[i] > bv) { bv = v[i]; bi = lane + i * 64; } }
      #pragma unroll
      for (int off = 32; off; off >>= 1) {
        float ov = __shfl_xor(bv, off, 64);
        int   oi = __shfl_xor(bi, off, 64);
        if (ov > bv || (ov == bv && oi < bi)) { bv = ov; bi = oi; }
      }
      ys[it] = (float)bi;
      if ((bi & 63) == lane) v[bi >> 6] = -INFINITY;
    }
    double ll = 0;
    if (lane < KK) {
      double y = (double)ys[lane];
      double a[KK], m = -1e300;
      #pragma unroll
      for (int j = 0; j < KK; j++) {
        double z = (y - (double)s_par[10 + j]) / (double)s_par[25 + j];
        a[j] = (double)s_par[j] - 0.5 * z * z - (double)s_par[15 + j]
               - 0.91893853320467274178;  // 0.5*log(2*pi)
        if (a[j] > m) m = a[j];
      }
      double se = 0;
      #pragma unroll
      for (int j = 0; j < KK; j++) se += exp(a[j] - m);
      ll = m + log(se);
    }
    ll = wredd(ll);
    if (lane == 0) loss_rows[n] = ll;
  }
  // mask: one token position per thread
  {
    float t = (float)tid, d = 0;
    #pragma unroll
    for (int k = 0; k < KK; k++) {
      float zt = (t - s_par[10 + k]) * s_par[20 + k];
      d += s_par[5 + k] * expf(-0.5f * zt * zt) * s_par[20 + k];
    }
    d *= 0.39894228040143268f;   // 1/sqrt(2*pi)
    mask_g[(size_t)n * LL + tid] = d;
    float r = wredf(d);
    if (lane == 0) s_dn[wid] = r;
  }
  __syncthreads();
  if (tid == 0)
    denom_g[n] = fmaxf(s_dn[0]+s_dn[1]+s_dn[2]+s_dn[3]+s_dn[4]+s_dn[5]+s_dn[6]+s_dn[7], 1e-9f);
}

// ==== node 3: pooling + fused sim/head via per-(b,p) num/zz atomics + last block
__global__ __launch_bounds__(512) void k3h(const float* __restrict__ hidden,
    const float* __restrict__ mask_g, const float* __restrict__ denom_g,
    const float* __restrict__ proto, const float* __restrict__ pnorm,
    const float* __restrict__ fcW, const float* __restrict__ fcb,
    const double* __restrict__ loss_rows, const float* __restrict__ divp,
    float* __restrict__ numzz, int* __restrict__ counter, float* __restrict__ out)
{
  __shared__ float s_m[PP][LL];        // 10 KB
  __shared__ float s_acc[8][PP][128];  // 20 KB
  __shared__ float s_red2[24];
  __shared__ float s_sim[NN];
  __shared__ int s_last;
  int b = blockIdx.x, hc = blockIdx.y;
  int tid = threadIdx.x, wid = tid >> 6, lane = tid & 63;
  for (int i = tid; i < PP * LL; i += 512) s_m[i >> 9][i & (LL - 1)] = mask_g[(size_t)b * PP * LL + i];
  __syncthreads();
  int h0 = hc * 128 + lane * 2;
  const float* hp = hidden + (size_t)b * LL * HH + h0;
  float a0[PP] = {0,0,0,0,0}, a1[PP] = {0,0,0,0,0};
  int lbase = wid * 64;
  #pragma unroll 8
  for (int i = 0; i < 64; i++) {
    int l = lbase + i;
    float2 hv = *(const float2*)(hp + (size_t)l * HH);
    #pragma unroll
    for (int p = 0; p < PP; p++) {
      float m = s_m[p][l];
      a0[p] = fmaf(hv.x, m, a0[p]); a1[p] = fmaf(hv.y, m, a1[p]);
    }
  }
  #pragma unroll
  for (int p = 0; p < PP; p++) { s_acc[wid][p][lane*2] = a0[p]; s_acc[wid][p][lane*2+1] = a1[p]; }
  __syncthreads();
  // epilogue: partial num = sum_h Z*proto, zz = sum_h Z^2 for this 128-h chunk.
  // Z = s/512/denom. Items: 5p x 128h = 640; iter1 = o in [0,512), iter2 = o in [512,640).
  {
    int p1 = tid >> 7, hl1 = tid & 127;       // wave w covers p1 = w>>1 (const per wave)
    float s = 0;
    #pragma unroll
    for (int w = 0; w < 8; w++) s += s_acc[w][p1][hl1];
    float z = s * (1.0f / 512.0f) / denom_g[b * PP + p1];
    float np1 = z * proto[p1 * HH + hc * 128 + hl1];
    float zp1 = z * z;
    np1 = wredf(np1); zp1 = wredf(zp1);
    if (lane == 0) { s_red2[wid * 2] = np1; s_red2[wid * 2 + 1] = zp1; }
  }
  {
    float np2 = 0, zp2 = 0;
    if (tid < 128) {                          // p = 4, waves 0..1
      float s = 0;
      #pragma unroll
      for (int w = 0; w < 8; w++) s += s_acc[w][4][tid];
      float z = s * (1.0f / 512.0f) / denom_g[b * PP + 4];
      np2 = z * proto[4 * HH + hc * 128 + tid];
      zp2 = z * z;
    }
    np2 = wredf(np2); zp2 = wredf(zp2);
    if (lane == 0 && wid < 2) { s_red2[16 + wid * 2] = np2; s_red2[17 + wid * 2] = zp2; }
  }
  __syncthreads();
  if (tid < 10) {
    int p = tid >> 1, r = tid & 1;
    float v = (p < 4) ? (s_red2[4 * p + r] + s_red2[4 * p + 2 + r])
                      : (s_red2[16 + r] + s_red2[18 + r]);
    atomicAdd(&numzz[(b * PP + p) * 2 + r], v);
  }
  // __syncthreads drains vmcnt -> all this block's atomics device-visible before counter bump
  __syncthreads();
  if (tid == 0) { __threadfence(); s_last = (atomicAdd(counter, 1) == (BB * 6 - 1)); }
  __syncthreads();
  if (s_last) {
    __threadfence();   // acquire: other blocks' numzz/loss writes
    for (int g = tid; g < NN; g += 512) {
      float num = numzz[2 * g], zz = numzz[2 * g + 1];
      s_sim[g] = num / fmaxf(sqrtf(zz) * pnorm[g % PP], 1e-6f);
    }
    __syncthreads();
    if (tid < BB * CC) {
      int bb2 = tid >> 2, c = tid & 3;
      float s = fcb[c];
      #pragma unroll
      for (int q = 0; q < PP; q++) s = fmaf(s_sim[bb2 * PP + q], fcW[q * CC + c], s);
      out[tid] = s;
    }
    if (wid == 2) {
      double s = 0;
      for (int i = lane; i < NN; i += 64) s += loss_rows[i];
      s = wredd(s);
      if (lane == 0) out[128] = (float)(-s / 800.0);
    }
    if (wid == 3) {
      float s = (lane < 10) ? divp[lane] : 0.0f;
      s = wredf(s);
      if (lane == 0) out[129] = s;
    }
  }
}

extern "C" void kernel_launch(void* const* d_in, const int* in_sizes, int n_in,
                              void* d_out, int out_size, void* d_ws, size_t ws_size,
                              hipStream_t stream)
{
  const float* emb   = (const float*)d_in[0];
  const float* hid   = (const float*)d_in[1];
  const float* proto = (const float*)d_in[2];
  const float* W1    = (const float*)d_in[3];
  const float* b1    = (const float*)d_in[4];
  const float* Wpi   = (const float*)d_in[5];
  const float* bpi   = (const float*)d_in[6];
  const float* Wmu   = (const float*)d_in[7];
  const float* bmu   = (const float*)d_in[8];
  const float* Wsig  = (const float*)d_in[9];
  const float* bsig  = (const float*)d_in[10];
  const float* fcW   = (const float*)d_in[11];
  const float* fcb   = (const float*)d_in[12];
  float* out = (float*)d_out;

  // ws layout (float offsets)
  double* loss_rows = (double*)d_ws;        // floats [0,320)
  float* wsf    = (float*)d_ws;
  float* divp   = wsf + 320;                // 10
  float* pnorm  = wsf + 330;                // 5
  int*   counter= (int*)(wsf + 336);        // 1
  float* numzz  = wsf + 352;                // 320 (num,zz per row)
  float* cs     = wsf + 1024;               // 81920
  float* maskb  = cs + (size_t)NN * LL;     // 81920
  float* denom  = maskb + (size_t)NN * LL;  // 160

  k1f<<<4112, 256, 0, stream>>>(emb, proto, cs, pnorm, divp, counter, numzz);
  k2f<<<NN, 512, 0, stream>>>(cs, pnorm, W1, b1, Wpi, bpi, Wmu, bmu, Wsig, bsig,
                              maskb, denom, loss_rows);
  k3h<<<dim3(BB, 6), 512, 0, stream>>>(hid, maskb, denom, proto, pnorm, fcW, fcb,
                                       loss_rows, divp, numzz, counter, out);
}